// Round 5
// baseline (451.401 us; speedup 1.0000x reference)
//
#include <hip/hip_runtime.h>

#define L1V 1444
#define LTOT 1768
#define CRV 32
#define CHV 64
#define HWV 1600
#define KT 24            // key tiles
#define KB 74            // keys per tile (last tile: 1768-23*74 = 66)
#define NQ 1536          // padded query count (6 waves * 256)

// ---------------- K1: base = prelu(w1·x), wf = prelu(w2·avgpool(x)), global sumsq ----------------
__global__ __launch_bounds__(256) void k_front(const float* __restrict__ x,
    const float* __restrict__ w1, const float* __restrict__ b1, const float* __restrict__ a1,
    const float* __restrict__ w2, const float* __restrict__ b2, const float* __restrict__ a2,
    float* __restrict__ base, float* __restrict__ wf, float* __restrict__ sumsq)
{
    int t = blockIdx.x * 256 + threadIdx.x;
    float sq = 0.f;
    if (t < CRV * HWV) {                      // blocks 0..199: base
        int c = t / HWV, px = t - c * HWV;
        float acc = b1[c];
        #pragma unroll 8
        for (int ic = 0; ic < CHV; ++ic) acc += w1[c * CHV + ic] * x[ic * HWV + px];
        float a = a1[0];
        float v = acc >= 0.f ? acc : a * acc;
        base[t] = v;
        sq = v * v;
    } else {                                   // blocks 200..249: wf
        int u = t - CRV * HWV;                 // < 12800
        int c = u / 400, p = u - c * 400;
        int i = p / 20, j = p - i * 20;
        int px0 = (2 * i) * 40 + 2 * j;
        float acc = b2[c];
        for (int ic = 0; ic < CHV; ++ic) {
            const float* xp = x + ic * HWV + px0;
            float xd = 0.25f * (xp[0] + xp[1] + xp[40] + xp[41]);
            acc += w2[c * CHV + ic] * xd;
        }
        float a = a2[0];
        float v = acc >= 0.f ? acc : a * acc;
        wf[u] = v;
        sq = v * v;
    }
    __shared__ float red[256];
    red[threadIdx.x] = sq;
    __syncthreads();
    for (int s = 128; s > 0; s >>= 1) {
        if (threadIdx.x < s) red[threadIdx.x] += red[threadIdx.x + s];
        __syncthreads();
    }
    if (threadIdx.x == 0) atomicAdd(&sumsq[blockIdx.x < 200 ? 0 : 1], red[0]);
}

// ---------------- K2: fused patch attention, key-tiled, atomic merge ----------------
// grid = (KT=24 key-tiles, 32 channels) = 768 blocks = 3 blocks/CU -> 18 waves/CU.
// block = 384 thr (6 waves). Wave w owns queries [w*256, w*256+256) (Q=4/lane),
// loaded from global. Block stages <=74 keys (2.7 KB LDS, broadcast reads).
// Each lane accumulates num[4][9]/den[4] over the tile and atomicAdds 10 floats
// per query into part[c][1444][10]. No cross-wave reduction.
__global__ __launch_bounds__(384, 4) void k_attn(const float* __restrict__ base,
    const float* __restrict__ wf, const float* __restrict__ sumsq,
    float* __restrict__ part)
{
    __shared__ __align__(16) float panA[KB * 4];
    __shared__ __align__(16) float panB[KB * 4];
    __shared__ float panC[KB];
    const int kt  = blockIdx.x;
    const int c   = blockIdx.y;
    const int tid = threadIdx.x;
    const float bmax = sqrtf(sumsq[0]);
    const float wmax = sqrtf(sumsq[1]);
    const float invb = 1.0f / bmax, invw = 1.0f / wmax;
    const float SC = 10.0f * 1.44269504088896f;   // SCALE * log2(e)

    const int k0 = kt * KB;
    const int kb = (k0 + KB <= LTOT) ? KB : (LTOT - k0);

    // stage this tile's keys into LDS (threads 0..kb-1)
    if (tid < kb) {
        int l = k0 + tid;
        const float* src;
        int stride;
        float scale;
        if (l < L1V) {
            int i = l / 38, j = l - i * 38;
            src = base + c * HWV + i * 40 + j;
            stride = 40; scale = invb;
        } else {
            int l2 = l - L1V;
            int i = l2 / 18, j = l2 - i * 18;
            src = wf + c * 400 + i * 20 + j;
            stride = 20; scale = invw;
        }
        float v0 = src[0]          * scale, v1 = src[1]          * scale, v2 = src[2]          * scale;
        float v3 = src[stride]     * scale, v4 = src[stride+1]   * scale, v5 = src[stride+2]   * scale;
        float v6 = src[2*stride]   * scale, v7 = src[2*stride+1] * scale, v8 = src[2*stride+2] * scale;
        *reinterpret_cast<float4*>(&panA[tid*4]) = make_float4(v0, v1, v2, v3);
        *reinterpret_cast<float4*>(&panB[tid*4]) = make_float4(v4, v5, v6, v7);
        panC[tid] = v8;
    }

    // load Q=4 query vectors from global (overlaps staging), pre-scaled by SC*norm
    const int lane = tid & 63;
    const int w    = tid >> 6;                 // 0..5
    float q[4][9];
    #pragma unroll
    for (int qi = 0; qi < 4; ++qi) {
        int m = w * 256 + qi * 64 + lane;      // < 1536, safe to read (wf region for m>=1444)
        const float* src;
        int stride;
        float scale;
        if (m < L1V) {
            int i = m / 38, j = m - i * 38;
            src = base + c * HWV + i * 40 + j;
            stride = 40; scale = invb * SC;
        } else {
            int m2 = m - L1V;
            int i = m2 / 18, j = m2 - i * 18;
            src = wf + c * 400 + i * 20 + j;
            stride = 20; scale = invw * SC;
        }
        q[qi][0] = src[0]          * scale; q[qi][1] = src[1]          * scale; q[qi][2] = src[2]          * scale;
        q[qi][3] = src[stride]     * scale; q[qi][4] = src[stride+1]   * scale; q[qi][5] = src[stride+2]   * scale;
        q[qi][6] = src[2*stride]   * scale; q[qi][7] = src[2*stride+1] * scale; q[qi][8] = src[2*stride+2] * scale;
    }
    __syncthreads();

    float num[4][9];
    float den[4] = {0.f, 0.f, 0.f, 0.f};
    #pragma unroll
    for (int qi = 0; qi < 4; ++qi)
        #pragma unroll
        for (int k = 0; k < 9; ++k) num[qi][k] = 0.f;

    // split tile at the base/wf boundary (global l = 1444)
    const int end = kb;
    const int B   = L1V - k0;                       // may be <0 or >kb
    const int e1  = (end < B) ? end : (B > 0 ? B : 0);
    const int s2  = e1;

    #define ATTN_ITER(VS)                                                     \
    {                                                                         \
        float4 A  = *reinterpret_cast<const float4*>(&panA[ll*4]);            \
        float4 Bv = *reinterpret_cast<const float4*>(&panB[ll*4]);            \
        float  c8 = panC[ll];                                                 \
        _Pragma("unroll")                                                     \
        for (int qi = 0; qi < 4; ++qi) {                                      \
            float sA = q[qi][0]*A.x + q[qi][1]*A.y;                           \
            sA = sA + q[qi][2]*A.z;                                           \
            sA = sA + q[qi][3]*A.w;                                           \
            float sB = q[qi][8]*c8 + q[qi][4]*Bv.x;                           \
            sB = sB + q[qi][5]*Bv.y;                                          \
            sB = sB + q[qi][6]*Bv.z;                                          \
            sB = sB + q[qi][7]*Bv.w;                                          \
            float p  = __builtin_amdgcn_exp2f(sA + sB);                       \
            float pv = p * (VS);                                              \
            den[qi] += p;                                                     \
            num[qi][0] += pv*A.x;  num[qi][1] += pv*A.y;                      \
            num[qi][2] += pv*A.z;  num[qi][3] += pv*A.w;                      \
            num[qi][4] += pv*Bv.x; num[qi][5] += pv*Bv.y;                     \
            num[qi][6] += pv*Bv.z; num[qi][7] += pv*Bv.w;                     \
            num[qi][8] += pv*c8;                                              \
        }                                                                     \
    }

    for (int ll = 0;  ll < e1;  ++ll) ATTN_ITER(bmax)
    for (int ll = s2; ll < end; ++ll) ATTN_ITER(wmax)
    #undef ATTN_ITER

    // merge partials across key-tiles via fp32 atomics (part is L2-resident, 1.85 MB)
    #pragma unroll
    for (int qi = 0; qi < 4; ++qi) {
        int m = w * 256 + qi * 64 + lane;
        if (m < L1V) {
            float* dst = part + ((size_t)c * L1V + m) * 10;
            #pragma unroll
            for (int k = 0; k < 9; ++k) atomicAdd(&dst[k], num[qi][k]);
            atomicAdd(&dst[9], den[qi]);
        }
    }
}

// ---------------- K2b: divide by den, layout to patches ----------------
__global__ __launch_bounds__(256) void k_comb(const float* __restrict__ part,
                                              float* __restrict__ patches)
{
    int t = blockIdx.x * 256 + threadIdx.x;
    if (t >= CRV * L1V) return;
    int c = t / L1V, m = t - c * L1V;
    const float* p0 = part + (size_t)t * 10;
    float inv = 1.0f / p0[9];
    #pragma unroll
    for (int k = 0; k < 9; ++k)
        patches[(c * 9 + k) * L1V + m] = p0[k] * inv;
}

// ---------------- K3: fold (sum overlapping patches) / 9 ----------------
__global__ __launch_bounds__(256) void k_fold(const float* __restrict__ patches,
                                              float* __restrict__ folded)
{
    int t = blockIdx.x * 256 + threadIdx.x;
    if (t >= CRV * HWV) return;
    int c = t / HWV, px = t - c * HWV;
    int h = px / 40, w = px - h * 40;
    float acc = 0.f;
    #pragma unroll
    for (int di = 0; di < 3; ++di) {
        int i = h - di;
        if (i < 0 || i >= 38) continue;
        #pragma unroll
        for (int dj = 0; dj < 3; ++dj) {
            int j = w - dj;
            if (j < 0 || j >= 38) continue;
            acc += patches[(c * 9 + di * 3 + dj) * L1V + i * 38 + j];
        }
    }
    folded[t] = acc * (1.0f / 9.0f);
}

// ---------------- K4: y = prelu(w3·folded + b3) + x ----------------
__global__ __launch_bounds__(256) void k_out(const float* __restrict__ folded,
    const float* __restrict__ w3, const float* __restrict__ b3, const float* __restrict__ a3,
    const float* __restrict__ x, float* __restrict__ out)
{
    int t = blockIdx.x * 256 + threadIdx.x;
    if (t >= CHV * HWV) return;
    int oc = t / HWV, px = t - oc * HWV;
    float acc = b3[oc];
    #pragma unroll
    for (int ic = 0; ic < CRV; ++ic) acc += w3[oc * CRV + ic] * folded[ic * HWV + px];
    float a = a3[0];
    float v = acc >= 0.f ? acc : a * acc;
    out[t] = v + x[t];
}

extern "C" void kernel_launch(void* const* d_in, const int* in_sizes, int n_in,
                              void* d_out, int out_size, void* d_ws, size_t ws_size,
                              hipStream_t stream)
{
    const float* x  = (const float*)d_in[0];
    const float* w1 = (const float*)d_in[1];
    const float* b1 = (const float*)d_in[2];
    const float* a1 = (const float*)d_in[3];
    const float* w2 = (const float*)d_in[4];
    const float* b2 = (const float*)d_in[5];
    const float* a2 = (const float*)d_in[6];
    const float* w3 = (const float*)d_in[7];
    const float* b3 = (const float*)d_in[8];
    const float* a3 = (const float*)d_in[9];

    float* ws      = (float*)d_ws;
    float* sumsq   = ws;                               // 2 floats (+pad to 64)
    float* base    = ws + 64;                          // 32*1600 = 51200
    float* wfb     = base + CRV * HWV;                 // 32*400  = 12800
    float* patches = wfb + 12800;                      // 32*9*1444 = 415872
    float* folded  = patches + CRV * 9 * L1V;          // 51200
    float* part    = folded + CRV * HWV;               // 32*1444*10 = 462080 (~1.85 MB)

    hipMemsetAsync(sumsq, 0, 2 * sizeof(float), stream);
    hipMemsetAsync(part, 0, (size_t)CRV * L1V * 10 * sizeof(float), stream);
    k_front<<<250, 256, 0, stream>>>(x, w1, b1, a1, w2, b2, a2, base, wfb, sumsq);
    k_attn<<<dim3(KT, CRV), 384, 0, stream>>>(base, wfb, sumsq, part);
    k_comb<<<181, 256, 0, stream>>>(part, patches);
    k_fold<<<200, 256, 0, stream>>>(patches, folded);
    k_out<<<400, 256, 0, stream>>>(folded, w3, b3, a3, x, (float*)d_out);
}

// Round 6
// 124.410 us; speedup vs baseline: 3.6283x; 3.6283x over previous
//
#include <hip/hip_runtime.h>

#define L1V 1444
#define LTOT 1768
#define LHALF 884
#define LB1 560          // within half 1: l_local 560 <=> global l 1444 (base/wf boundary)
#define CRV 32
#define CHV 64
#define HWV 1600

// ---------------- K1: base = prelu(w1·x), wf = prelu(w2·avgpool(x)), global sumsq ----------------
__global__ __launch_bounds__(256) void k_front(const float* __restrict__ x,
    const float* __restrict__ w1, const float* __restrict__ b1, const float* __restrict__ a1,
    const float* __restrict__ w2, const float* __restrict__ b2, const float* __restrict__ a2,
    float* __restrict__ base, float* __restrict__ wf, float* __restrict__ sumsq)
{
    int t = blockIdx.x * 256 + threadIdx.x;
    float sq = 0.f;
    if (t < CRV * HWV) {                      // blocks 0..199: base
        int c = t / HWV, px = t - c * HWV;
        float acc = b1[c];
        #pragma unroll 8
        for (int ic = 0; ic < CHV; ++ic) acc += w1[c * CHV + ic] * x[ic * HWV + px];
        float a = a1[0];
        float v = acc >= 0.f ? acc : a * acc;
        base[t] = v;
        sq = v * v;
    } else {                                   // blocks 200..249: wf
        int u = t - CRV * HWV;                 // < 12800
        int c = u / 400, p = u - c * 400;
        int i = p / 20, j = p - i * 20;
        int px0 = (2 * i) * 40 + 2 * j;
        float acc = b2[c];
        for (int ic = 0; ic < CHV; ++ic) {
            const float* xp = x + ic * HWV + px0;
            float xd = 0.25f * (xp[0] + xp[1] + xp[40] + xp[41]);
            acc += w2[c * CHV + ic] * xd;
        }
        float a = a2[0];
        float v = acc >= 0.f ? acc : a * acc;
        wf[u] = v;
        sq = v * v;
    }
    __shared__ float red[256];
    red[threadIdx.x] = sq;
    __syncthreads();
    for (int s = 128; s > 0; s >>= 1) {
        if (threadIdx.x < s) red[threadIdx.x] += red[threadIdx.x + s];
        __syncthreads();
    }
    if (threadIdx.x == 0) atomicAdd(&sumsq[blockIdx.x < 200 ? 0 : 1], red[0]);
}

// ---------------- K2: fused per-channel patch attention, key-split ----------------
// grid = (8 qtiles x 32 channels x 2 key-halves) = 512 blocks = 2 blocks/CU
// -> 16 waves/CU = 4 waves/SIMD. block = 512 thr (8 waves). Lane owns Q=3
// queries (from global); wave w handles ~110 keys of the block's 884-key half
// (staged in LDS, 31.8 KB). waves_per_eu(4,4) relaxes the allocator to 128
// VGPR so q[27]+num[27]+den[3] stay in arch VGPRs (R4 had VGPR=52 -> AGPR
// shuttling, ~1.7x VALU inflation). Cross-wave merge via LDS ds_add_f32
// into a [192][10] region aliased over pan; halves merged by k_comb.
__global__ __launch_bounds__(512) __attribute__((amdgpu_waves_per_eu(4, 4)))
void k_attn(const float* __restrict__ base,
    const float* __restrict__ wf, const float* __restrict__ sumsq,
    float* __restrict__ part)
{
    __shared__ __align__(16) float lds[7956];     // 31,824 B
    float* panA = lds;                            // [884][4] k=0..3
    float* panB = lds + 3536;                     // [884][4] k=4..7
    float* panC = lds + 7072;                     // [884]    k=8
    const int c    = blockIdx.y;
    const int qb   = blockIdx.x;
    const int half = blockIdx.z;
    const int tid  = threadIdx.x;
    const float bmax = sqrtf(sumsq[0]);
    const float wmax = sqrtf(sumsq[1]);
    const float invb = 1.0f / bmax, invw = 1.0f / wmax;
    const float SC = 10.0f * 1.44269504088896f;   // SCALE * log2(e)

    // stage this half's pan keys into LDS
    const int lbase = half * LHALF;
    for (int ll = tid; ll < LHALF; ll += 512) {
        int l = lbase + ll;
        const float* src;
        int stride;
        float scale;
        if (l < L1V) {
            int i = l / 38, j = l - i * 38;
            src = base + c * HWV + i * 40 + j;
            stride = 40; scale = invb;
        } else {
            int l2 = l - L1V;
            int i = l2 / 18, j = l2 - i * 18;
            src = wf + c * 400 + i * 20 + j;
            stride = 20; scale = invw;
        }
        float v0 = src[0]          * scale, v1 = src[1]          * scale, v2 = src[2]          * scale;
        float v3 = src[stride]     * scale, v4 = src[stride+1]   * scale, v5 = src[stride+2]   * scale;
        float v6 = src[2*stride]   * scale, v7 = src[2*stride+1] * scale, v8 = src[2*stride+2] * scale;
        *reinterpret_cast<float4*>(&panA[ll*4]) = make_float4(v0, v1, v2, v3);
        *reinterpret_cast<float4*>(&panB[ll*4]) = make_float4(v4, v5, v6, v7);
        panC[ll] = v8;
    }

    // load Q=3 query vectors straight from global (overlaps with staging above),
    // pre-scaled by SCALE*log2(e)*norm
    const int lane = tid & 63;
    const int w    = tid >> 6;
    float q[3][9];
    #pragma unroll
    for (int qi = 0; qi < 3; ++qi) {
        int m = qb * 192 + qi * 64 + lane;         // < 1536 <= 1768, safe
        const float* src;
        int stride;
        float scale;
        if (m < L1V) {
            int i = m / 38, j = m - i * 38;
            src = base + c * HWV + i * 40 + j;
            stride = 40; scale = invb * SC;
        } else {
            int m2 = m - L1V;
            int i = m2 / 18, j = m2 - i * 18;
            src = wf + c * 400 + i * 20 + j;
            stride = 20; scale = invw * SC;
        }
        q[qi][0] = src[0]          * scale; q[qi][1] = src[1]          * scale; q[qi][2] = src[2]          * scale;
        q[qi][3] = src[stride]     * scale; q[qi][4] = src[stride+1]   * scale; q[qi][5] = src[stride+2]   * scale;
        q[qi][6] = src[2*stride]   * scale; q[qi][7] = src[2*stride+1] * scale; q[qi][8] = src[2*stride+2] * scale;
    }
    __syncthreads();

    float num[3][9];
    float den[3] = {0.f, 0.f, 0.f};
    #pragma unroll
    for (int qi = 0; qi < 3; ++qi)
        #pragma unroll
        for (int k = 0; k < 9; ++k) num[qi][k] = 0.f;

    // wave's key segment within the half: 884 = 8*110 + 4
    const int start = w * 110 + (w < 4 ? w : 4);
    const int end   = start + 110 + (w < 4 ? 1 : 0);
    const int B     = (half == 0) ? LHALF : LB1;   // base/wf boundary in local coords
    const int e1    = end < B ? end : B;
    const int s2    = start > B ? start : B;

    // base segment: accumulate raw p (defer *bmax to a one-time epilogue scale)
    for (int l = start; l < e1; ++l) {
        float4 A  = *reinterpret_cast<const float4*>(&panA[l*4]);
        float4 Bv = *reinterpret_cast<const float4*>(&panB[l*4]);
        float  c8 = panC[l];
        #pragma unroll
        for (int qi = 0; qi < 3; ++qi) {
            float sA = q[qi][0]*A.x + q[qi][1]*A.y;
            sA = sA + q[qi][2]*A.z;
            sA = sA + q[qi][3]*A.w;
            float sB = q[qi][8]*c8 + q[qi][4]*Bv.x;
            sB = sB + q[qi][5]*Bv.y;
            sB = sB + q[qi][6]*Bv.z;
            sB = sB + q[qi][7]*Bv.w;
            float p  = __builtin_amdgcn_exp2f(sA + sB);
            den[qi] += p;
            num[qi][0] += p*A.x;  num[qi][1] += p*A.y;
            num[qi][2] += p*A.z;  num[qi][3] += p*A.w;
            num[qi][4] += p*Bv.x; num[qi][5] += p*Bv.y;
            num[qi][6] += p*Bv.z; num[qi][7] += p*Bv.w;
            num[qi][8] += p*c8;
        }
    }
    #pragma unroll
    for (int qi = 0; qi < 3; ++qi)
        #pragma unroll
        for (int k = 0; k < 9; ++k) num[qi][k] *= bmax;

    // wf segment: scale inside (short for most waves)
    for (int l = s2; l < end; ++l) {
        float4 A  = *reinterpret_cast<const float4*>(&panA[l*4]);
        float4 Bv = *reinterpret_cast<const float4*>(&panB[l*4]);
        float  c8 = panC[l];
        #pragma unroll
        for (int qi = 0; qi < 3; ++qi) {
            float sA = q[qi][0]*A.x + q[qi][1]*A.y;
            sA = sA + q[qi][2]*A.z;
            sA = sA + q[qi][3]*A.w;
            float sB = q[qi][8]*c8 + q[qi][4]*Bv.x;
            sB = sB + q[qi][5]*Bv.y;
            sB = sB + q[qi][6]*Bv.z;
            sB = sB + q[qi][7]*Bv.w;
            float p  = __builtin_amdgcn_exp2f(sA + sB);
            float pv = p * wmax;
            den[qi] += p;
            num[qi][0] += pv*A.x;  num[qi][1] += pv*A.y;
            num[qi][2] += pv*A.z;  num[qi][3] += pv*A.w;
            num[qi][4] += pv*Bv.x; num[qi][5] += pv*Bv.y;
            num[qi][6] += pv*Bv.z; num[qi][7] += pv*Bv.w;
            num[qi][8] += pv*c8;
        }
    }

    // cross-wave merge via LDS atomics (region aliases pan, done being read)
    __syncthreads();
    float* red = lds;                // [192][10] = 7,680 B
    for (int i = tid; i < 1920; i += 512) red[i] = 0.f;
    __syncthreads();
    #pragma unroll
    for (int qi = 0; qi < 3; ++qi) {
        float* dst = red + (qi * 64 + lane) * 10;
        #pragma unroll
        for (int k = 0; k < 9; ++k) atomicAdd(&dst[k], num[qi][k]);
        atomicAdd(&dst[9], den[qi]);
    }
    __syncthreads();

    if (tid < 192) {
        float* dst = part + ((size_t)(half * CRV + c) * 1536 + qb * 192 + tid) * 10;
        #pragma unroll
        for (int j = 0; j < 10; ++j) dst[j] = red[tid * 10 + j];
    }
}

// ---------------- K2b: merge key-halves, divide by den ----------------
__global__ __launch_bounds__(256) void k_comb(const float* __restrict__ part,
                                              float* __restrict__ patches)
{
    int t = blockIdx.x * 256 + threadIdx.x;
    if (t >= CRV * L1V) return;
    int c = t / L1V, m = t - c * L1V;
    const float* p0 = part + (size_t)c         * 15360 + m * 10;
    const float* p1 = part + (size_t)(CRV + c) * 15360 + m * 10;
    float tot[10];
    #pragma unroll
    for (int j = 0; j < 10; ++j) tot[j] = p0[j] + p1[j];
    float inv = 1.0f / tot[9];
    #pragma unroll
    for (int k = 0; k < 9; ++k)
        patches[(c * 9 + k) * L1V + m] = tot[k] * inv;
}

// ---------------- K3: fold (sum overlapping patches) / 9 ----------------
__global__ __launch_bounds__(256) void k_fold(const float* __restrict__ patches,
                                              float* __restrict__ folded)
{
    int t = blockIdx.x * 256 + threadIdx.x;
    if (t >= CRV * HWV) return;
    int c = t / HWV, px = t - c * HWV;
    int h = px / 40, w = px - h * 40;
    float acc = 0.f;
    #pragma unroll
    for (int di = 0; di < 3; ++di) {
        int i = h - di;
        if (i < 0 || i >= 38) continue;
        #pragma unroll
        for (int dj = 0; dj < 3; ++dj) {
            int j = w - dj;
            if (j < 0 || j >= 38) continue;
            acc += patches[(c * 9 + di * 3 + dj) * L1V + i * 38 + j];
        }
    }
    folded[t] = acc * (1.0f / 9.0f);
}

// ---------------- K4: y = prelu(w3·folded + b3) + x ----------------
__global__ __launch_bounds__(256) void k_out(const float* __restrict__ folded,
    const float* __restrict__ w3, const float* __restrict__ b3, const float* __restrict__ a3,
    const float* __restrict__ x, float* __restrict__ out)
{
    int t = blockIdx.x * 256 + threadIdx.x;
    if (t >= CHV * HWV) return;
    int oc = t / HWV, px = t - oc * HWV;
    float acc = b3[oc];
    #pragma unroll
    for (int ic = 0; ic < CRV; ++ic) acc += w3[oc * CRV + ic] * folded[ic * HWV + px];
    float a = a3[0];
    float v = acc >= 0.f ? acc : a * acc;
    out[t] = v + x[t];
}

extern "C" void kernel_launch(void* const* d_in, const int* in_sizes, int n_in,
                              void* d_out, int out_size, void* d_ws, size_t ws_size,
                              hipStream_t stream)
{
    const float* x  = (const float*)d_in[0];
    const float* w1 = (const float*)d_in[1];
    const float* b1 = (const float*)d_in[2];
    const float* a1 = (const float*)d_in[3];
    const float* w2 = (const float*)d_in[4];
    const float* b2 = (const float*)d_in[5];
    const float* a2 = (const float*)d_in[6];
    const float* w3 = (const float*)d_in[7];
    const float* b3 = (const float*)d_in[8];
    const float* a3 = (const float*)d_in[9];

    float* ws      = (float*)d_ws;
    float* sumsq   = ws;                               // 2 floats (+pad to 64)
    float* base    = ws + 64;                          // 32*1600 = 51200
    float* wfb     = base + CRV * HWV;                 // 32*400  = 12800
    float* patches = wfb + 12800;                      // 32*9*1444 = 415872
    float* folded  = patches + CRV * 9 * L1V;          // 51200
    float* part    = folded + CRV * HWV;               // 2*32*1536*10 = 983040 (~3.9 MB)

    hipMemsetAsync(sumsq, 0, 2 * sizeof(float), stream);
    k_front<<<250, 256, 0, stream>>>(x, w1, b1, a1, w2, b2, a2, base, wfb, sumsq);
    k_attn<<<dim3(8, 32, 2), 512, 0, stream>>>(base, wfb, sumsq, part);
    k_comb<<<181, 256, 0, stream>>>(part, patches);
    k_fold<<<200, 256, 0, stream>>>(patches, folded);
    k_out<<<400, 256, 0, stream>>>(folded, w3, b3, a3, x, (float*)d_out);
}

// Round 7
// 74.830 us; speedup vs baseline: 6.0323x; 1.6626x over previous
//
#include <hip/hip_runtime.h>

#define L1V 1444
#define LTOT 1768
#define LHALF 884
#define LB1 560          // within half 1: l_local 560 <=> global l 1444 (base/wf boundary)
#define CRV 32
#define CHV 64
#define HWV 1600

// ---------------- K1: base = prelu(w1·x), wf = prelu(w2·avgpool(x)), global sumsq ----------------
__global__ __launch_bounds__(256) void k_front(const float* __restrict__ x,
    const float* __restrict__ w1, const float* __restrict__ b1, const float* __restrict__ a1,
    const float* __restrict__ w2, const float* __restrict__ b2, const float* __restrict__ a2,
    float* __restrict__ base, float* __restrict__ wf, float* __restrict__ sumsq)
{
    int t = blockIdx.x * 256 + threadIdx.x;
    float sq = 0.f;
    if (t < CRV * HWV) {                      // blocks 0..199: base
        int c = t / HWV, px = t - c * HWV;
        float acc = b1[c];
        #pragma unroll 8
        for (int ic = 0; ic < CHV; ++ic) acc += w1[c * CHV + ic] * x[ic * HWV + px];
        float a = a1[0];
        float v = acc >= 0.f ? acc : a * acc;
        base[t] = v;
        sq = v * v;
    } else {                                   // blocks 200..249: wf
        int u = t - CRV * HWV;                 // < 12800
        int c = u / 400, p = u - c * 400;
        int i = p / 20, j = p - i * 20;
        int px0 = (2 * i) * 40 + 2 * j;
        float acc = b2[c];
        for (int ic = 0; ic < CHV; ++ic) {
            const float* xp = x + ic * HWV + px0;
            float xd = 0.25f * (xp[0] + xp[1] + xp[40] + xp[41]);
            acc += w2[c * CHV + ic] * xd;
        }
        float a = a2[0];
        float v = acc >= 0.f ? acc : a * acc;
        wf[u] = v;
        sq = v * v;
    }
    __shared__ float red[256];
    red[threadIdx.x] = sq;
    __syncthreads();
    for (int s = 128; s > 0; s >>= 1) {
        if (threadIdx.x < s) red[threadIdx.x] += red[threadIdx.x + s];
        __syncthreads();
    }
    if (threadIdx.x == 0) atomicAdd(&sumsq[blockIdx.x < 200 ? 0 : 1], red[0]);
}

// ---------------- K2: fused per-channel patch attention, key-split ----------------
// R4 geometry (65.5us proven): grid = (8 qtiles x 32 ch x 2 key-halves) = 512
// blocks = 2 blocks/CU = 4 waves/SIMD. block = 512 thr (8 waves). Lane owns
// Q=3 queries; wave w handles ~110 keys of the block's 884-key half (LDS).
// Non-atomic overlay merge (R6's LDS-atomic merge = 8-way same-address
// serialization, +45us — reverted).
// NEW vs R4: (a) explicit fmaf in the hot loop; (b) empty inline-asm ties
// pin all q[27]+s[3] (and pv[3]) in arch VGPRs each iteration -> forbids
// the allocator's qi-sectioning/AGPR-shuttle (theory: source of the 1.9x
// VALU inflation at VGPR=52); (c) __launch_bounds__(512,4) caps VGPR at 128
// (4 waves/SIMD * 128 = full pool) so occupancy stays 2 blocks/CU.
__global__ __launch_bounds__(512, 4) void k_attn(const float* __restrict__ base,
    const float* __restrict__ wf, const float* __restrict__ sumsq,
    float* __restrict__ part)
{
    __shared__ __align__(16) float lds[15360];   // 61,440 B (pan + reduction overlay)
    float* panA = lds;                            // [884][4] k=0..3
    float* panB = lds + 3536;                     // [884][4] k=4..7
    float* panC = lds + 7072;                     // [884]    k=8
    const int c    = blockIdx.y;
    const int qb   = blockIdx.x;
    const int half = blockIdx.z;
    const int tid  = threadIdx.x;
    const float bmax = sqrtf(sumsq[0]);
    const float wmax = sqrtf(sumsq[1]);
    const float invb = 1.0f / bmax, invw = 1.0f / wmax;
    const float SC = 10.0f * 1.44269504088896f;   // SCALE * log2(e)

    // stage this half's pan keys into LDS
    const int lbase = half * LHALF;
    for (int ll = tid; ll < LHALF; ll += 512) {
        int l = lbase + ll;
        const float* src;
        int stride;
        float scale;
        if (l < L1V) {
            int i = l / 38, j = l - i * 38;
            src = base + c * HWV + i * 40 + j;
            stride = 40; scale = invb;
        } else {
            int l2 = l - L1V;
            int i = l2 / 18, j = l2 - i * 18;
            src = wf + c * 400 + i * 20 + j;
            stride = 20; scale = invw;
        }
        float v0 = src[0]          * scale, v1 = src[1]          * scale, v2 = src[2]          * scale;
        float v3 = src[stride]     * scale, v4 = src[stride+1]   * scale, v5 = src[stride+2]   * scale;
        float v6 = src[2*stride]   * scale, v7 = src[2*stride+1] * scale, v8 = src[2*stride+2] * scale;
        *reinterpret_cast<float4*>(&panA[ll*4]) = make_float4(v0, v1, v2, v3);
        *reinterpret_cast<float4*>(&panB[ll*4]) = make_float4(v4, v5, v6, v7);
        panC[ll] = v8;
    }

    // load Q=3 query vectors straight from global, pre-scaled by SC*norm
    const int lane = tid & 63;
    const int w    = tid >> 6;
    float q[3][9];
    #pragma unroll
    for (int qi = 0; qi < 3; ++qi) {
        int m = qb * 192 + qi * 64 + lane;         // < 1536 <= 1768, safe
        const float* src;
        int stride;
        float scale;
        if (m < L1V) {
            int i = m / 38, j = m - i * 38;
            src = base + c * HWV + i * 40 + j;
            stride = 40; scale = invb * SC;
        } else {
            int m2 = m - L1V;
            int i = m2 / 18, j = m2 - i * 18;
            src = wf + c * 400 + i * 20 + j;
            stride = 20; scale = invw * SC;
        }
        q[qi][0] = src[0]          * scale; q[qi][1] = src[1]          * scale; q[qi][2] = src[2]          * scale;
        q[qi][3] = src[stride]     * scale; q[qi][4] = src[stride+1]   * scale; q[qi][5] = src[stride+2]   * scale;
        q[qi][6] = src[2*stride]   * scale; q[qi][7] = src[2*stride+1] * scale; q[qi][8] = src[2*stride+2] * scale;
    }
    __syncthreads();

    float num[3][9];
    float den[3] = {0.f, 0.f, 0.f};
    #pragma unroll
    for (int qi = 0; qi < 3; ++qi)
        #pragma unroll
        for (int k = 0; k < 9; ++k) num[qi][k] = 0.f;

    // wave's key segment within the half: 884 = 8*110 + 4
    const int start = w * 110 + (w < 4 ? w : 4);
    const int end   = start + 110 + (w < 4 ? 1 : 0);
    const int B     = (half == 0) ? LHALF : LB1;   // base/wf boundary in local coords
    const int e1    = end < B ? end : B;
    const int s2    = start > B ? start : B;

    #define ATTN_ITER(VS)                                                      \
    {                                                                          \
        float4 A  = *reinterpret_cast<const float4*>(&panA[l*4]);              \
        float4 Bv = *reinterpret_cast<const float4*>(&panB[l*4]);              \
        float  c8 = panC[l];                                                   \
        float s0a = fmaf(q[0][1], A.y,  q[0][0]*A.x);                          \
        float s1a = fmaf(q[1][1], A.y,  q[1][0]*A.x);                          \
        float s2a = fmaf(q[2][1], A.y,  q[2][0]*A.x);                          \
        float s0b = fmaf(q[0][4], Bv.x, q[0][8]*c8);                           \
        float s1b = fmaf(q[1][4], Bv.x, q[1][8]*c8);                           \
        float s2b = fmaf(q[2][4], Bv.x, q[2][8]*c8);                           \
        s0a = fmaf(q[0][2], A.z, s0a);  s1a = fmaf(q[1][2], A.z, s1a);         \
        s2a = fmaf(q[2][2], A.z, s2a);                                         \
        s0b = fmaf(q[0][5], Bv.y, s0b); s1b = fmaf(q[1][5], Bv.y, s1b);        \
        s2b = fmaf(q[2][5], Bv.y, s2b);                                        \
        s0a = fmaf(q[0][3], A.w, s0a);  s1a = fmaf(q[1][3], A.w, s1a);         \
        s2a = fmaf(q[2][3], A.w, s2a);                                         \
        s0b = fmaf(q[0][6], Bv.z, s0b); s1b = fmaf(q[1][6], Bv.z, s1b);        \
        s2b = fmaf(q[2][6], Bv.z, s2b);                                        \
        s0b = fmaf(q[0][7], Bv.w, s0b); s1b = fmaf(q[1][7], Bv.w, s1b);        \
        s2b = fmaf(q[2][7], Bv.w, s2b);                                        \
        float s0 = s0a + s0b, s1 = s1a + s1b, s2 = s2a + s2b;                  \
        asm volatile("" : "+v"(s0), "+v"(s1), "+v"(s2),                        \
            "+v"(q[0][0]), "+v"(q[0][1]), "+v"(q[0][2]), "+v"(q[0][3]),        \
            "+v"(q[0][4]), "+v"(q[0][5]), "+v"(q[0][6]), "+v"(q[0][7]),        \
            "+v"(q[0][8]),                                                     \
            "+v"(q[1][0]), "+v"(q[1][1]), "+v"(q[1][2]), "+v"(q[1][3]),        \
            "+v"(q[1][4]), "+v"(q[1][5]), "+v"(q[1][6]), "+v"(q[1][7]),        \
            "+v"(q[1][8]),                                                     \
            "+v"(q[2][0]), "+v"(q[2][1]), "+v"(q[2][2]), "+v"(q[2][3]),        \
            "+v"(q[2][4]), "+v"(q[2][5]), "+v"(q[2][6]), "+v"(q[2][7]),        \
            "+v"(q[2][8]));                                                    \
        float p0 = __builtin_amdgcn_exp2f(s0);                                 \
        float p1 = __builtin_amdgcn_exp2f(s1);                                 \
        float p2 = __builtin_amdgcn_exp2f(s2);                                 \
        float pv0 = p0 * (VS), pv1 = p1 * (VS), pv2 = p2 * (VS);               \
        asm volatile("" : "+v"(pv0), "+v"(pv1), "+v"(pv2));                    \
        den[0] += p0; den[1] += p1; den[2] += p2;                              \
        num[0][0] = fmaf(pv0, A.x,  num[0][0]);                                \
        num[1][0] = fmaf(pv1, A.x,  num[1][0]);                                \
        num[2][0] = fmaf(pv2, A.x,  num[2][0]);                                \
        num[0][1] = fmaf(pv0, A.y,  num[0][1]);                                \
        num[1][1] = fmaf(pv1, A.y,  num[1][1]);                                \
        num[2][1] = fmaf(pv2, A.y,  num[2][1]);                                \
        num[0][2] = fmaf(pv0, A.z,  num[0][2]);                                \
        num[1][2] = fmaf(pv1, A.z,  num[1][2]);                                \
        num[2][2] = fmaf(pv2, A.z,  num[2][2]);                                \
        num[0][3] = fmaf(pv0, A.w,  num[0][3]);                                \
        num[1][3] = fmaf(pv1, A.w,  num[1][3]);                                \
        num[2][3] = fmaf(pv2, A.w,  num[2][3]);                                \
        num[0][4] = fmaf(pv0, Bv.x, num[0][4]);                                \
        num[1][4] = fmaf(pv1, Bv.x, num[1][4]);                                \
        num[2][4] = fmaf(pv2, Bv.x, num[2][4]);                                \
        num[0][5] = fmaf(pv0, Bv.y, num[0][5]);                                \
        num[1][5] = fmaf(pv1, Bv.y, num[1][5]);                                \
        num[2][5] = fmaf(pv2, Bv.y, num[2][5]);                                \
        num[0][6] = fmaf(pv0, Bv.z, num[0][6]);                                \
        num[1][6] = fmaf(pv1, Bv.z, num[1][6]);                                \
        num[2][6] = fmaf(pv2, Bv.z, num[2][6]);                                \
        num[0][7] = fmaf(pv0, Bv.w, num[0][7]);                                \
        num[1][7] = fmaf(pv1, Bv.w, num[1][7]);                                \
        num[2][7] = fmaf(pv2, Bv.w, num[2][7]);                                \
        num[0][8] = fmaf(pv0, c8,   num[0][8]);                                \
        num[1][8] = fmaf(pv1, c8,   num[1][8]);                                \
        num[2][8] = fmaf(pv2, c8,   num[2][8]);                                \
    }

    for (int l = start; l < e1; ++l) ATTN_ITER(bmax)
    for (int l = s2;    l < end; ++l) ATTN_ITER(wmax)
    #undef ATTN_ITER

    __syncthreads();                 // pan no longer needed; overlay partials
    float* red = lds;                // [8 waves][192 q][10] = 61,440 B
    #pragma unroll
    for (int qi = 0; qi < 3; ++qi) {
        float* myp = red + (w * 192 + qi * 64 + lane) * 10;
        #pragma unroll
        for (int k = 0; k < 9; ++k) myp[k] = num[qi][k];
        myp[9] = den[qi];
    }
    __syncthreads();

    if (tid < 192) {
        float tot[10];
        #pragma unroll
        for (int j = 0; j < 10; ++j) {
            float s = 0.f;
            #pragma unroll
            for (int ww = 0; ww < 8; ++ww) s += red[(ww * 192 + tid) * 10 + j];
            tot[j] = s;
        }
        float* dst = part + ((size_t)(half * CRV + c) * 1536 + qb * 192 + tid) * 10;
        #pragma unroll
        for (int j = 0; j < 10; ++j) dst[j] = tot[j];
    }
}

// ---------------- K2b: merge key-halves, divide by den ----------------
__global__ __launch_bounds__(256) void k_comb(const float* __restrict__ part,
                                              float* __restrict__ patches)
{
    int t = blockIdx.x * 256 + threadIdx.x;
    if (t >= CRV * L1V) return;
    int c = t / L1V, m = t - c * L1V;
    const float* p0 = part + (size_t)c         * 15360 + m * 10;
    const float* p1 = part + (size_t)(CRV + c) * 15360 + m * 10;
    float tot[10];
    #pragma unroll
    for (int j = 0; j < 10; ++j) tot[j] = p0[j] + p1[j];
    float inv = 1.0f / tot[9];
    #pragma unroll
    for (int k = 0; k < 9; ++k)
        patches[(c * 9 + k) * L1V + m] = tot[k] * inv;
}

// ---------------- K3: fold (sum overlapping patches) / 9 ----------------
__global__ __launch_bounds__(256) void k_fold(const float* __restrict__ patches,
                                              float* __restrict__ folded)
{
    int t = blockIdx.x * 256 + threadIdx.x;
    if (t >= CRV * HWV) return;
    int c = t / HWV, px = t - c * HWV;
    int h = px / 40, w = px - h * 40;
    float acc = 0.f;
    #pragma unroll
    for (int di = 0; di < 3; ++di) {
        int i = h - di;
        if (i < 0 || i >= 38) continue;
        #pragma unroll
        for (int dj = 0; dj < 3; ++dj) {
            int j = w - dj;
            if (j < 0 || j >= 38) continue;
            acc += patches[(c * 9 + di * 3 + dj) * L1V + i * 38 + j];
        }
    }
    folded[t] = acc * (1.0f / 9.0f);
}

// ---------------- K4: y = prelu(w3·folded + b3) + x ----------------
__global__ __launch_bounds__(256) void k_out(const float* __restrict__ folded,
    const float* __restrict__ w3, const float* __restrict__ b3, const float* __restrict__ a3,
    const float* __restrict__ x, float* __restrict__ out)
{
    int t = blockIdx.x * 256 + threadIdx.x;
    if (t >= CHV * HWV) return;
    int oc = t / HWV, px = t - oc * HWV;
    float acc = b3[oc];
    #pragma unroll
    for (int ic = 0; ic < CRV; ++ic) acc += w3[oc * CRV + ic] * folded[ic * HWV + px];
    float a = a3[0];
    float v = acc >= 0.f ? acc : a * acc;
    out[t] = v + x[t];
}

extern "C" void kernel_launch(void* const* d_in, const int* in_sizes, int n_in,
                              void* d_out, int out_size, void* d_ws, size_t ws_size,
                              hipStream_t stream)
{
    const float* x  = (const float*)d_in[0];
    const float* w1 = (const float*)d_in[1];
    const float* b1 = (const float*)d_in[2];
    const float* a1 = (const float*)d_in[3];
    const float* w2 = (const float*)d_in[4];
    const float* b2 = (const float*)d_in[5];
    const float* a2 = (const float*)d_in[6];
    const float* w3 = (const float*)d_in[7];
    const float* b3 = (const float*)d_in[8];
    const float* a3 = (const float*)d_in[9];

    float* ws      = (float*)d_ws;
    float* sumsq   = ws;                               // 2 floats (+pad to 64)
    float* base    = ws + 64;                          // 32*1600 = 51200
    float* wfb     = base + CRV * HWV;                 // 32*400  = 12800
    float* patches = wfb + 12800;                      // 32*9*1444 = 415872
    float* folded  = patches + CRV * 9 * L1V;          // 51200
    float* part    = folded + CRV * HWV;               // 2*32*1536*10 = 983040 (~3.9 MB)

    hipMemsetAsync(sumsq, 0, 2 * sizeof(float), stream);
    k_front<<<250, 256, 0, stream>>>(x, w1, b1, a1, w2, b2, a2, base, wfb, sumsq);
    k_attn<<<dim3(8, 32, 2), 512, 0, stream>>>(base, wfb, sumsq, part);
    k_comb<<<181, 256, 0, stream>>>(part, patches);
    k_fold<<<200, 256, 0, stream>>>(patches, folded);
    k_out<<<400, 256, 0, stream>>>(folded, w3, b3, a3, x, (float*)d_out);
}

// Round 9
// 45.445 us; speedup vs baseline: 9.9329x; 1.6466x over previous
//
#include <hip/hip_runtime.h>

#define L1V 1444
#define CRV 32
#define CHV 64
#define HWV 1600
#define KHALF 896        // key slots per half (padded: base 1444->1456, wf 324->336)
#define ROWH 20          // f16 per LDS row (40 B -> conflict-free b64 frag reads)
#define NQT 91           // real query tiles (1456/16)

typedef float    f32x4 __attribute__((ext_vector_type(4)));
typedef _Float16 f16x4 __attribute__((ext_vector_type(4)));

// ---------------- K1: base = prelu(w1·x), wf = prelu(w2·avgpool(x)), global sumsq ----------------
__global__ __launch_bounds__(256) void k_front(const float* __restrict__ x,
    const float* __restrict__ w1, const float* __restrict__ b1, const float* __restrict__ a1,
    const float* __restrict__ w2, const float* __restrict__ b2, const float* __restrict__ a2,
    float* __restrict__ base, float* __restrict__ wf, float* __restrict__ sumsq)
{
    int t = blockIdx.x * 256 + threadIdx.x;
    float sq = 0.f;
    if (t < CRV * HWV) {                      // blocks 0..199: base
        int c = t / HWV, px = t - c * HWV;
        float acc = b1[c];
        #pragma unroll 8
        for (int ic = 0; ic < CHV; ++ic) acc += w1[c * CHV + ic] * x[ic * HWV + px];
        float a = a1[0];
        float v = acc >= 0.f ? acc : a * acc;
        base[t] = v;
        sq = v * v;
    } else {                                   // blocks 200..249: wf
        int u = t - CRV * HWV;                 // < 12800
        int c = u / 400, p = u - c * 400;
        int i = p / 20, j = p - i * 20;
        int px0 = (2 * i) * 40 + 2 * j;
        float acc = b2[c];
        for (int ic = 0; ic < CHV; ++ic) {
            const float* xp = x + ic * HWV + px0;
            float xd = 0.25f * (xp[0] + xp[1] + xp[40] + xp[41]);
            acc += w2[c * CHV + ic] * xd;
        }
        float a = a2[0];
        float v = acc >= 0.f ? acc : a * acc;
        wf[u] = v;
        sq = v * v;
    }
    __shared__ float red[256];
    red[threadIdx.x] = sq;
    __syncthreads();
    for (int s = 128; s > 0; s >>= 1) {
        if (threadIdx.x < s) red[threadIdx.x] += red[threadIdx.x + s];
        __syncthreads();
    }
    if (threadIdx.x == 0) atomicAdd(&sumsq[blockIdx.x < 200 ? 0 : 1], red[0]);
}

// ---------------- K2: MFMA flash-style patch attention ----------------
// grid = (12 qtile-groups, 32 ch, 2 key-halves) = 768 blocks = 3/CU exact.
// block = 256 thr (4 waves); wave owns 2 q-tiles of 16 queries.
// Keys staged in LDS as [896][20] f16 rows: k=0..8 normalized pan, k=9 = 1.0
// (ones column -> den comes free in PV col 9; zero on padded rows), k>=10 = 0.
// Per 16-key tile: S^T = mfma(A=keys, B=queries) leaves P[q=lane%16][l] exactly
// in the PV A-fragment layout (in-lane), so QK -> exp2 -> cvt -> PV needs
// no shuffles. Two f32x4 accumulators (base/wf segments, tile-aligned split);
// epilogue: num = bmax*accB + wmax*accW, den = accB[9]+accW[9] -> ws partials.
__global__ __launch_bounds__(256) void k_attn(const float* __restrict__ base,
    const float* __restrict__ wf, const float* __restrict__ sumsq,
    float* __restrict__ part)
{
    __shared__ _Float16 panL[KHALF * ROWH];   // 35,840 B
    const int qg   = blockIdx.x;              // 0..11
    const int c    = blockIdx.y;
    const int half = blockIdx.z;
    const int tid  = threadIdx.x;
    const float bmax = sqrtf(sumsq[0]);
    const float wmax = sqrtf(sumsq[1]);
    const float invb = 1.0f / bmax, invw = 1.0f / wmax;
    const float SC = 14.4269504089f;          // SCALE * log2(e)

    // ---- stage this half's key slots ----
    for (int s = tid; s < KHALF; s += 256) {
        int g = half * KHALF + s;
        float v[9];
        float one = 0.f;
        if (g < L1V) {
            int i = g / 38, j = g - i * 38;
            const float* src = base + c * HWV + i * 40 + j;
            #pragma unroll
            for (int kh = 0; kh < 3; ++kh)
                #pragma unroll
                for (int kw = 0; kw < 3; ++kw) v[kh * 3 + kw] = src[kh * 40 + kw] * invb;
            one = 1.f;
        } else if (g >= 1456 && g < 1780) {
            int l2 = g - 1456;
            int i = l2 / 18, j = l2 - i * 18;
            const float* src = wf + c * 400 + i * 20 + j;
            #pragma unroll
            for (int kh = 0; kh < 3; ++kh)
                #pragma unroll
                for (int kw = 0; kw < 3; ++kw) v[kh * 3 + kw] = src[kh * 20 + kw] * invw;
            one = 1.f;
        } else {
            #pragma unroll
            for (int k = 0; k < 9; ++k) v[k] = 0.f;
        }
        f16x4 r0, r1, r2a, r3, r4;
        r0[0] = (_Float16)v[0]; r0[1] = (_Float16)v[1]; r0[2] = (_Float16)v[2]; r0[3] = (_Float16)v[3];
        r1[0] = (_Float16)v[4]; r1[1] = (_Float16)v[5]; r1[2] = (_Float16)v[6]; r1[3] = (_Float16)v[7];
        r2a[0] = (_Float16)v[8]; r2a[1] = (_Float16)one; r2a[2] = (_Float16)0.f; r2a[3] = (_Float16)0.f;
        r3 = (f16x4)(_Float16)0.f; r4 = (f16x4)(_Float16)0.f;
        _Float16* row = &panL[s * ROWH];
        *(f16x4*)&row[0]  = r0;
        *(f16x4*)&row[4]  = r1;
        *(f16x4*)&row[8]  = r2a;
        *(f16x4*)&row[12] = r3;
        *(f16x4*)&row[16] = r4;
    }

    // ---- query fragments (B operand), 2 q-tiles per wave, from global ----
    const int lane = tid & 63, w = tid >> 6;   // wave 0..3
    const int g16 = lane >> 4, c16 = lane & 15;
    f16x4 qf[2];
    int qtile[2];
    #pragma unroll
    for (int u = 0; u < 2; ++u) {
        qtile[u] = qg * 8 + w * 2 + u;         // 0..95 (>=91 garbage)
        int m = qtile[u] * 16 + c16;           // query index (base patches only)
        #pragma unroll
        for (int j = 0; j < 4; ++j) {
            int k = g16 * 4 + j;
            float val = 0.f;
            if (k <= 8 && m < L1V && qtile[u] < NQT) {
                int i = m / 38, jj = m - i * 38;
                val = base[c * HWV + (i + k / 3) * 40 + (jj + k % 3)] * invb * SC;
            }
            qf[u][j] = (_Float16)val;          // k=9..15 zero: ones-col can't leak into scores
        }
    }
    __syncthreads();

    f32x4 accB[2] = {{0.f,0.f,0.f,0.f},{0.f,0.f,0.f,0.f}};
    f32x4 accW[2] = {{0.f,0.f,0.f,0.f},{0.f,0.f,0.f,0.f}};
    const int BT = half ? 35 : 56;             // base-segment tiles in this half

    #define ATTN_TILE(ACC)                                                        \
    {                                                                             \
        const int rb = lt * 16;                                                   \
        f16x4 af = *(const f16x4*)&panL[(rb + c16) * ROWH + g16 * 4];             \
        const int r2 = rb + g16 * 4;                                              \
        f16x4 b2;                                                                 \
        b2[0] = panL[(r2 + 0) * ROWH + c16];                                      \
        b2[1] = panL[(r2 + 1) * ROWH + c16];                                      \
        b2[2] = panL[(r2 + 2) * ROWH + c16];                                      \
        b2[3] = panL[(r2 + 3) * ROWH + c16];                                      \
        _Pragma("unroll")                                                         \
        for (int u = 0; u < 2; ++u) {                                             \
            f32x4 d1 = __builtin_amdgcn_mfma_f32_16x16x16f16(af, qf[u],           \
                           (f32x4){0.f,0.f,0.f,0.f}, 0, 0, 0);                    \
            f16x4 a2;                                                             \
            a2[0] = (_Float16)__builtin_amdgcn_exp2f(d1[0]);                      \
            a2[1] = (_Float16)__builtin_amdgcn_exp2f(d1[1]);                      \
            a2[2] = (_Float16)__builtin_amdgcn_exp2f(d1[2]);                      \
            a2[3] = (_Float16)__builtin_amdgcn_exp2f(d1[3]);                      \
            ACC[u] = __builtin_amdgcn_mfma_f32_16x16x16f16(a2, b2, ACC[u],        \
                                                           0, 0, 0);              \
        }                                                                         \
    }

    for (int lt = 0;  lt < BT; ++lt) ATTN_TILE(accB)
    for (int lt = BT; lt < 56; ++lt) ATTN_TILE(accW)
    #undef ATTN_TILE

    // ---- epilogue: partial num/den per (query, half) -> ws ----
    if (c16 < 10) {
        #pragma unroll
        for (int u = 0; u < 2; ++u) {
            if (qtile[u] >= NQT) continue;
            #pragma unroll
            for (int i = 0; i < 4; ++i) {
                int qs = qtile[u] * 16 + g16 * 4 + i;
                if (qs < L1V) {
                    float v = (c16 == 9) ? (accB[u][i] + accW[u][i])
                                         : fmaf(bmax, accB[u][i], wmax * accW[u][i]);
                    part[((size_t)(half * CRV + c) * 1536 + qs) * 10 + c16] = v;
                }
            }
        }
    }
}

// ---------------- K2b: merge key-halves, divide by den ----------------
__global__ __launch_bounds__(256) void k_comb(const float* __restrict__ part,
                                              float* __restrict__ patches)
{
    int t = blockIdx.x * 256 + threadIdx.x;
    if (t >= CRV * L1V) return;
    int c = t / L1V, m = t - c * L1V;
    const float* p0 = part + (size_t)c         * 15360 + m * 10;
    const float* p1 = part + (size_t)(CRV + c) * 15360 + m * 10;
    float tot[10];
    #pragma unroll
    for (int j = 0; j < 10; ++j) tot[j] = p0[j] + p1[j];
    float inv = 1.0f / tot[9];
    #pragma unroll
    for (int k = 0; k < 9; ++k)
        patches[(c * 9 + k) * L1V + m] = tot[k] * inv;
}

// ---------------- K3: fold (sum overlapping patches) / 9 ----------------
__global__ __launch_bounds__(256) void k_fold(const float* __restrict__ patches,
                                              float* __restrict__ folded)
{
    int t = blockIdx.x * 256 + threadIdx.x;
    if (t >= CRV * HWV) return;
    int c = t / HWV, px = t - c * HWV;
    int h = px / 40, w = px - h * 40;
    float acc = 0.f;
    #pragma unroll
    for (int di = 0; di < 3; ++di) {
        int i = h - di;
        if (i < 0 || i >= 38) continue;
        #pragma unroll
        for (int dj = 0; dj < 3; ++dj) {
            int j = w - dj;
            if (j < 0 || j >= 38) continue;
            acc += patches[(c * 9 + di * 3 + dj) * L1V + i * 38 + j];
        }
    }
    folded[t] = acc * (1.0f / 9.0f);
}

// ---------------- K4: y = prelu(w3·folded + b3) + x ----------------
__global__ __launch_bounds__(256) void k_out(const float* __restrict__ folded,
    const float* __restrict__ w3, const float* __restrict__ b3, const float* __restrict__ a3,
    const float* __restrict__ x, float* __restrict__ out)
{
    int t = blockIdx.x * 256 + threadIdx.x;
    if (t >= CHV * HWV) return;
    int oc = t / HWV, px = t - oc * HWV;
    float acc = b3[oc];
    #pragma unroll
    for (int ic = 0; ic < CRV; ++ic) acc += w3[oc * CRV + ic] * folded[ic * HWV + px];
    float a = a3[0];
    float v = acc >= 0.f ? acc : a * acc;
    out[t] = v + x[t];
}

extern "C" void kernel_launch(void* const* d_in, const int* in_sizes, int n_in,
                              void* d_out, int out_size, void* d_ws, size_t ws_size,
                              hipStream_t stream)
{
    const float* x  = (const float*)d_in[0];
    const float* w1 = (const float*)d_in[1];
    const float* b1 = (const float*)d_in[2];
    const float* a1 = (const float*)d_in[3];
    const float* w2 = (const float*)d_in[4];
    const float* b2 = (const float*)d_in[5];
    const float* a2 = (const float*)d_in[6];
    const float* w3 = (const float*)d_in[7];
    const float* b3 = (const float*)d_in[8];
    const float* a3 = (const float*)d_in[9];

    float* ws      = (float*)d_ws;
    float* sumsq   = ws;                               // 2 floats (+pad to 64)
    float* base    = ws + 64;                          // 32*1600 = 51200
    float* wfb     = base + CRV * HWV;                 // 32*400  = 12800
    float* patches = wfb + 12800;                      // 32*9*1444 = 415872
    float* folded  = patches + CRV * 9 * L1V;          // 51200
    float* part    = folded + CRV * HWV;               // 2*32*1536*10 = 983040

    hipMemsetAsync(sumsq, 0, 2 * sizeof(float), stream);
    k_front<<<250, 256, 0, stream>>>(x, w1, b1, a1, w2, b2, a2, base, wfb, sumsq);
    k_attn<<<dim3(12, CRV, 2), 256, 0, stream>>>(base, wfb, sumsq, part);
    k_comb<<<181, 256, 0, stream>>>(part, patches);
    k_fold<<<200, 256, 0, stream>>>(patches, folded);
    k_out<<<400, 256, 0, stream>>>(folded, w3, b3, a3, x, (float*)d_out);
}